// Round 8
// baseline (1408.594 us; speedup 1.0000x reference)
//
#include <hip/hip_runtime.h>

// ---------- types ----------
typedef short v8s __attribute__((ext_vector_type(8)));
typedef float v4f __attribute__((ext_vector_type(4)));

static __device__ __forceinline__ unsigned short f2bf(float x) {
    unsigned u = __builtin_bit_cast(unsigned, x);
    unsigned r = (u + 0x7fffu + ((u >> 16) & 1u)) >> 16;
    return (unsigned short)r;
}

static __device__ __forceinline__ float sigm(float x) {
    return 1.f / (1.f + __expf(-x));
}
static __device__ __forceinline__ float tanh_fast(float x) {
    x = fminf(fmaxf(x, -15.f), 15.f);
    float e = __expf(2.f * x);
    return (e - 1.f) / (e + 1.f);
}

// ---------- elementwise f32 -> bf16 convert ----------
__global__ void cvt_bf16(const float* __restrict__ src, unsigned short* __restrict__ dst, int n) {
    int i = blockIdx.x * 256 + threadIdx.x;
    if (i < n) dst[i] = f2bf(src[i]);
}

// ---------- repack W_hh (f32 [1536][512]) into MFMA B-fragment order ----------
__global__ void repack_whh(const float* __restrict__ src, unsigned short* __restrict__ dst) {
    long e = (long)blockIdx.x * 256 + threadIdx.x;  // < 786432
    int i = e & 7;
    int lane = (e >> 3) & 63;
    int kf = (e >> 9) & 15;
    int T = (int)(e >> 13);  // 0..95
    int gcol = T * 16 + (lane & 15);
    int k = kf * 32 + (lane >> 4) * 8 + i;
    dst[e] = f2bf(src[(long)gcol * 512 + k]);
}

// ---------- zero team flags (every launch, incl. graph replays) ----------
__global__ void init_flags(unsigned int* __restrict__ p) {
    p[threadIdx.x] = 0;
}

// ---------- build X = concat(embed_table[slot_ids], value_embeds) as bf16 [16384][1024] ----------
__global__ void build_x(const int* __restrict__ slot_ids,
                        const float* __restrict__ value_embeds,
                        const float* __restrict__ embed_table,
                        unsigned short* __restrict__ X) {
    int r = blockIdx.x;           // r = b*64 + s
    int t = threadIdx.x;          // 256 threads
    int id = slot_ids[r];
    X[(long)r * 1024 + t] = f2bf(embed_table[id * 256 + t]);
#pragma unroll
    for (int i = 0; i < 3; i++) {
        int c = t + i * 256;
        X[(long)r * 1024 + 256 + c] = f2bf(value_embeds[(long)r * 768 + c]);
    }
}

// ---------- bf16 MFMA GEMM: C[M][N] = A[M][K] * Bt[N][K]^T ----------
// EPI=0: plain f32 store. EPI=1: scatter gi packed: [d][s][bg 8][cb 16][wave 4][g 3][lane 64][r 4]
template <int EPI>
__global__ __launch_bounds__(256) void gemm_bt(const unsigned short* __restrict__ A,
                                               const unsigned short* __restrict__ Bt,
                                               float* __restrict__ C,
                                               int M, int N, int K) {
    const int LDT = 72;
    __shared__ unsigned short As[128 * 72];
    __shared__ unsigned short Bs[128 * 72];
    int tid = threadIdx.x;
    int lane = tid & 63;
    int wave = tid >> 6;
    int gm0 = blockIdx.y * 128;
    int gn0 = blockIdx.x * 128;
    int wm0 = (wave >> 1) * 64;
    int wn0 = (wave & 1) * 64;
    int q = lane >> 4;
    int l16 = lane & 15;

    v4f acc[4][4];
#pragma unroll
    for (int i = 0; i < 4; i++)
#pragma unroll
        for (int j = 0; j < 4; j++) acc[i][j] = v4f{0.f, 0.f, 0.f, 0.f};

    for (int k0 = 0; k0 < K; k0 += 64) {
#pragma unroll
        for (int l = tid; l < 1024; l += 256) {
            int row = l >> 3;
            int col = (l & 7) * 8;
            *(v8s*)&As[row * LDT + col] = *(const v8s*)&A[(long)(gm0 + row) * K + k0 + col];
            *(v8s*)&Bs[row * LDT + col] = *(const v8s*)&Bt[(long)(gn0 + row) * K + k0 + col];
        }
        __syncthreads();
#pragma unroll
        for (int kf = 0; kf < 2; kf++) {
            v8s af[4], bfr[4];
#pragma unroll
            for (int mi = 0; mi < 4; mi++)
                af[mi] = *(const v8s*)&As[(wm0 + mi * 16 + l16) * LDT + kf * 32 + q * 8];
#pragma unroll
            for (int ni = 0; ni < 4; ni++)
                bfr[ni] = *(const v8s*)&Bs[(wn0 + ni * 16 + l16) * LDT + kf * 32 + q * 8];
#pragma unroll
            for (int mi = 0; mi < 4; mi++)
#pragma unroll
                for (int ni = 0; ni < 4; ni++)
                    acc[mi][ni] = __builtin_amdgcn_mfma_f32_16x16x32_bf16(af[mi], bfr[ni], acc[mi][ni], 0, 0, 0);
        }
        __syncthreads();
    }

#pragma unroll
    for (int mi = 0; mi < 4; mi++)
#pragma unroll
        for (int ni = 0; ni < 4; ni++) {
            int col = gn0 + wn0 + ni * 16 + l16;
#pragma unroll
            for (int r = 0; r < 4; r++) {
                int row = gm0 + wm0 + mi * 16 + q * 4 + r;
                float v = acc[mi][ni][r];
                if (EPI == 0) {
                    C[(long)row * N + col] = v;
                } else {
                    int dd = (col >= 1536) ? 1 : 0;
                    int gcol = col - dd * 1536;
                    int g = gcol >> 9;
                    int jj = gcol & 511;
                    int cb = jj >> 5;
                    int jc = jj & 31;
                    int jh = jc >> 4;
                    int l16c = jc & 15;
                    int b = row >> 6, s = row & 63;
                    int bg = b >> 5, brow = b & 31;
                    int rgc = brow >> 4, m = brow & 15;
                    int qc = m >> 2, rc = m & 3;
                    int wv = rgc * 2 + jh;
                    long idx = (((((long)(dd * 64 + s) * 8 + bg) * 16 + cb) * 4 + wv) * 3 + g) * 256 +
                               (qc * 16 + l16c) * 4 + rc;
                    C[idx] = v;
                }
            }
        }
}

// ---------- GRU recurrence: W in LDS, h-share in A-fragment layout, direct frag loads ----
// 256 blocks x 256 threads (1/CU). blk = d*128 + bg*16 + cb. team=(d,bg): 16 blocks split
// 512 h-cols. h-share per team: 2 slots x [rg 2][kf 16][lane 64][8] bf16 (32KB/slot).
// Producer scatters shfl-packed dwords (sc0 sc1 write-through) into frag order; consumer
// wave: relaxed flag poll -> ONE agent acquire fence (buffer_inv) -> 16 plain dwordx4
// fragment loads (compiler batches; single waitcnt). ONE barrier/step (pre-flag drain).
extern __shared__ __align__(16) char smem[];
__global__ __launch_bounds__(256) void gru_rec(const float* __restrict__ gi,           // packed, see EPI=1
                                               const unsigned short* __restrict__ Wpk, // [2][96][16][64][8]
                                               const float* __restrict__ bih_f,
                                               const float* __restrict__ bhh_f,
                                               const float* __restrict__ bih_b,
                                               const float* __restrict__ bhh_b,
                                               unsigned short* __restrict__ hout,      // [256][64][1024]
                                               unsigned int* __restrict__ hshd,        // [16][2][8192] dwords
                                               unsigned int* __restrict__ flags) {     // [16][16]
    unsigned short* Wl = (unsigned short*)smem;  // [6 slots][16 kf][64 lane][8] = 96 KB
    int tid = threadIdx.x;
    int lane = tid & 63;
    int wave = tid >> 6;          // 0..3
    int q = lane >> 4, l16 = lane & 15;
    int blk = blockIdx.x;
    int d = blk >> 7;
    int bg = (blk >> 4) & 7;
    int cb = blk & 15;
    int team = d * 8 + bg;
    int rg = wave >> 1, jh = wave & 1;
    int j = cb * 32 + jh * 16 + l16;   // owned h-col

    // W slice -> LDS (B-frag order); slot = g*2+jh
    for (int i = tid; i < 6 * 1024; i += 256) {
        int tile = i >> 10;
        int off = i & 1023;
        int gt = (tile >> 1) * 32 + cb * 2 + (tile & 1);
        *(v8s*)&Wl[(long)tile * 8192 + off * 8] = *(const v8s*)&Wpk[((long)d * 96 + gt) * 8192 + off * 8];
    }

    float bi[3], bh[3];
    {
        const float* bihp = d ? bih_b : bih_f;
        const float* bhhp = d ? bhh_b : bhh_f;
#pragma unroll
        for (int g = 0; g < 3; g++) {
            bi[g] = bihp[g * 512 + j];
            bh[g] = bhhp[g * 512 + j];
        }
    }
    float hreg[4] = {0.f, 0.f, 0.f, 0.f};

    unsigned int* myflags = flags + team * 16;
    unsigned int* hsteam = hshd + (long)team * 2 * 8192;  // dwords
    __syncthreads();

    for (int t = 0; t < 64; t++) {
        int s = d ? (63 - t) : t;

        // gi: 3 coalesced v4f nontemporal loads (issued early; overlap poll)
        const float* gp = gi + (((((long)(d * 64 + s)) * 8 + bg) * 16 + cb) * 4 + wave) * 768 + lane * 4;
        v4f gir[3];
#pragma unroll
        for (int g = 0; g < 3; g++)
            gir[g] = __builtin_nontemporal_load((const v4f*)(gp + g * 256));

        v4f acc[3];
#pragma unroll
        for (int g = 0; g < 3; g++) acc[g] = v4f{0.f, 0.f, 0.f, 0.f};

        if (t > 0) {
            // per-wave poll: all 16 team flags >= t (relaxed; no cache traffic beyond the line)
            while (true) {
                unsigned v = (lane < 16)
                                 ? __hip_atomic_load(&myflags[lane], __ATOMIC_RELAXED, __HIP_MEMORY_SCOPE_AGENT)
                                 : (unsigned)t;
                if (__ballot(v < (unsigned)t) == 0) break;
                __builtin_amdgcn_s_sleep(1);
            }
            // one acquire: drains, invalidates stale L1/L2 lines; then plain loads are fresh
            __builtin_amdgcn_fence(__ATOMIC_ACQUIRE, "agent");

            // direct A-fragment loads from slot (t-1)&1: 16 plain dwordx4, compiler-batched
            const v8s* ap = (const v8s*)((const char*)(hsteam + ((t + 1) & 1) * 8192) +
                                         rg * 16384 + lane * 16);
            v8s af[16];
#pragma unroll
            for (int kf = 0; kf < 16; kf++) af[kf] = ap[(long)kf * 64];

#pragma unroll
            for (int kf = 0; kf < 16; kf++) {
#pragma unroll
                for (int g = 0; g < 3; g++) {
                    v8s b = *(const v8s*)&Wl[(((long)(g * 2 + jh) * 16 + kf) * 64 + lane) * 8];
                    acc[g] = __builtin_amdgcn_mfma_f32_16x16x32_bf16(af[kf], b, acc[g], 0, 0, 0);
                }
            }
        }

        // combine + write h (A-frag layout in global share, sc0 sc1) + hout
        unsigned int* dst = hsteam + (t & 1) * 8192;
#pragma unroll
        for (int r = 0; r < 4; r++) {
            int row = rg * 16 + q * 4 + r;
            float rr = sigm(gir[0][r] + bi[0] + acc[0][r] + bh[0]);
            float zz = sigm(gir[1][r] + bi[1] + acc[1][r] + bh[1]);
            float nn = tanh_fast(gir[2][r] + bi[2] + rr * (acc[2][r] + bh[2]));
            float hn = (1.f - zz) * nn + zz * hreg[r];
            hreg[r] = hn;
            unsigned short hv = f2bf(hn);
            float pv = __shfl_xor(hn, 1);
            if ((lane & 1) == 0) {
                unsigned int pack = (unsigned int)hv | ((unsigned int)f2bf(pv) << 16);
                // final output (plain store; flushed at kernel end, gemm2 reads after)
                ((unsigned int*)hout)[(((long)(bg * 32 + row) * 64 + s) * 1024 + d * 512 + j) >> 1] = pack;
                // h-share scatter in A-frag order: kf slot = cb
                int dwIdx = (((rg * 16 + cb) * 64) + (jh * 2 + (l16 >> 3)) * 16 + q * 4 + r) * 4 +
                            ((l16 & 7) >> 1);
                __hip_atomic_store(&dst[dwIdx], pack, __ATOMIC_RELAXED, __HIP_MEMORY_SCOPE_AGENT);
            }
        }
        __syncthreads();  // per-wave vmcnt(0): all sc0/sc1 stores globally visible
        if (tid == 0)
            __hip_atomic_store(&myflags[cb], (unsigned)(t + 1), __ATOMIC_RELEASE,
                               __HIP_MEMORY_SCOPE_AGENT);
    }
}

extern "C" void kernel_launch(void* const* d_in, const int* in_sizes, int n_in,
                              void* d_out, int out_size, void* d_ws, size_t ws_size,
                              hipStream_t stream) {
    const int* slot_ids = (const int*)d_in[0];
    const float* value_embeds = (const float*)d_in[1];
    const float* embed_table = (const float*)d_in[2];
    const float* W_ih_f = (const float*)d_in[3];
    const float* W_hh_f = (const float*)d_in[4];
    const float* b_ih_f = (const float*)d_in[5];
    const float* b_hh_f = (const float*)d_in[6];
    const float* W_ih_b = (const float*)d_in[7];
    const float* W_hh_b = (const float*)d_in[8];
    const float* b_ih_b = (const float*)d_in[9];
    const float* b_hh_b = (const float*)d_in[10];
    const float* W_proj = (const float*)d_in[11];
    float* out = (float*)d_out;
    char* ws = (char*)d_ws;

    // workspace layout (bytes)
    unsigned short* X = (unsigned short*)(ws + 0);              // 16384x1024 bf16 = 33,554,432
    float* gi = (float*)(ws + 33554432);                        // 50,331,648 f32 = 201,326,592
    unsigned short* Wstk = (unsigned short*)(ws + 234881024);   // 3072x1024 bf16 = 6,291,456 (dead after gemm1)
    unsigned short* Wpk = (unsigned short*)(ws + 241172480);    // 2x96x16x64x8 bf16 = 3,145,728
    unsigned short* Wp = (unsigned short*)(ws + 244318208);     // 512x1024 bf16 = 1,048,576
    unsigned short* hout = X;  // alias: X dead after gemm1
    // h-share + flags alias the (dead-after-gemm1) Wstk region
    unsigned int* hshd = (unsigned int*)Wstk;                   // 16*2*8192 dwords = 1 MB
    unsigned int* flags = (unsigned int*)(ws + 234881024 + 1048576);  // 256 dwords

    const int SMEM = 98304;  // W slice only
    (void)hipFuncSetAttribute((const void*)gru_rec, hipFuncAttributeMaxDynamicSharedMemorySize, SMEM);

    cvt_bf16<<<6144, 256, 0, stream>>>(W_ih_f, Wstk, 1536 * 1024);
    cvt_bf16<<<6144, 256, 0, stream>>>(W_ih_b, Wstk + 1536 * 1024, 1536 * 1024);
    repack_whh<<<3072, 256, 0, stream>>>(W_hh_f, Wpk);
    repack_whh<<<3072, 256, 0, stream>>>(W_hh_b, Wpk + 786432);
    cvt_bf16<<<2048, 256, 0, stream>>>(W_proj, Wp, 512 * 1024);
    build_x<<<16384, 256, 0, stream>>>(slot_ids, value_embeds, embed_table, X);

    // gi = X @ [Wih_f; Wih_b]^T  (M=16384, N=3072, K=1024), packed epilogue
    gemm_bt<1><<<dim3(24, 128), 256, 0, stream>>>(X, Wstk, gi, 16384, 3072, 1024);

    // zero flags (after gemm1: aliases Wstk region)
    init_flags<<<1, 256, 0, stream>>>(flags);

    // recurrence: 256 co-resident blocks, W in LDS, direct frag h exchange
    gru_rec<<<256, 256, SMEM, stream>>>(gi, Wpk, b_ih_f, b_hh_f, b_ih_b, b_hh_b, hout, hshd, flags);

    // out = hcat @ W_proj^T   (M=16384, N=512, K=1024)
    gemm_bt<0><<<dim3(4, 128), 256, 0, stream>>>(hout, Wp, out, 16384, 512, 1024);
}